// Round 5
// baseline (1899.730 us; speedup 1.0000x reference)
//
#include <hip/hip_runtime.h>
#include <math.h>

#define B_ 8
#define CIN_ 128
#define COUT_ 256
#define N_ 8192
#define M_ 2048
#define K_ 16

#define GEMM_BLOCKS 2048   // 8 b * (8192/128 n-tiles) * (256/64 o-tiles)

// ---------------------------------------------------------------------------
// DPP wave reductions (row_shr 1/2/4/8 + row_bcast 15/31): VALU-latency only.
// (R1/v4 exact form — measured best fps: 1510us, VALUBusy at the 8-CU issue
// bound. R3's combined-u64 chain + ds_max_u64 was 30 instr vs 26 and slower.)
// ---------------------------------------------------------------------------
__device__ __forceinline__ unsigned umax2(unsigned a, unsigned b) { return a > b ? a : b; }
__device__ __forceinline__ unsigned umin2(unsigned a, unsigned b) { return a < b ? a : b; }

__device__ __forceinline__ unsigned wave_reduce_umax(unsigned v) {
    v = umax2(v, (unsigned)__builtin_amdgcn_update_dpp(0, (int)v, 0x111, 0xf, 0xf, false));
    v = umax2(v, (unsigned)__builtin_amdgcn_update_dpp(0, (int)v, 0x112, 0xf, 0xf, false));
    v = umax2(v, (unsigned)__builtin_amdgcn_update_dpp(0, (int)v, 0x114, 0xf, 0xf, false));
    v = umax2(v, (unsigned)__builtin_amdgcn_update_dpp(0, (int)v, 0x118, 0xf, 0xf, false));
    v = umax2(v, (unsigned)__builtin_amdgcn_update_dpp(0, (int)v, 0x142, 0xf, 0xf, false));
    v = umax2(v, (unsigned)__builtin_amdgcn_update_dpp(0, (int)v, 0x143, 0xf, 0xf, false));
    return (unsigned)__builtin_amdgcn_readlane((int)v, 63);
}
__device__ __forceinline__ unsigned wave_reduce_umin(unsigned v) {
    v = umin2(v, (unsigned)__builtin_amdgcn_update_dpp(-1, (int)v, 0x111, 0xf, 0xf, false));
    v = umin2(v, (unsigned)__builtin_amdgcn_update_dpp(-1, (int)v, 0x112, 0xf, 0xf, false));
    v = umin2(v, (unsigned)__builtin_amdgcn_update_dpp(-1, (int)v, 0x114, 0xf, 0xf, false));
    v = umin2(v, (unsigned)__builtin_amdgcn_update_dpp(-1, (int)v, 0x118, 0xf, 0xf, false));
    v = umin2(v, (unsigned)__builtin_amdgcn_update_dpp(-1, (int)v, 0x142, 0xf, 0xf, false));
    v = umin2(v, (unsigned)__builtin_amdgcn_update_dpp(-1, (int)v, 0x143, 0xf, 0xf, false));
    return (unsigned)__builtin_amdgcn_readlane((int)v, 63);
}

// ---------------------------------------------------------------------------
// MEGA kernel: blocks 0..7 = FPS (R1/v4 verbatim), blocks 8..8+2047 = GEMM.
// FPS occupies 8 CUs for ~1.5ms; GEMM (no dependency on FPS) fills the other
// 248 CUs concurrently (R4-verified: GEMM fully hidden, mega dur == fps dur).
// LDS union = max(139.4KB fps, 49KB gemm): a GEMM block can never co-reside
// with an FPS block, so FPS CUs stay dedicated. GEMM blocks also zero the
// counts histogram (stream-ordered before knn's atomics). FPS decision math
// FROZEN; GEMM accumulation order per output element unchanged.
// ---------------------------------------------------------------------------
__global__ __launch_bounds__(512) void fps_gemm_kernel(const float* __restrict__ coords,
                                                       const float* __restrict__ x,
                                                       const float* __restrict__ W,
                                                       float* __restrict__ fpts,
                                                       float* __restrict__ out_fps,
                                                       float* __restrict__ hp,
                                                       int* __restrict__ counts) {
    __shared__ union {
        struct {
            float4 pts[N_];                      // 128 KiB
            unsigned long long kbuf[2][8];
            int wlist[M_];                       // 8 KiB
        } f;
        struct {
            float Xs[64][128];                   // 32 KiB
            float Wt[64][68];                    // 17 KiB
        } g;
    } sm;

    const int tid = threadIdx.x;

    if (blockIdx.x < B_) {
        // ================= FPS (R1/v4 exact) =================
#pragma clang fp contract(off)
        const int b = blockIdx.x;
        const int lane = tid & 63;
        const int wid = tid >> 6;                // 0..7
        const float* cb = coords + (size_t)b * 3 * N_;
        float4* pts = sm.f.pts;
        unsigned long long (*kbuf)[8] = sm.f.kbuf;
        int* wlist = sm.f.wlist;

        float px[16], py[16], pz[16], mind[16];
#pragma unroll
        for (int s = 0; s < 16; ++s) {
            int p = tid + s * 512;
            px[s] = cb[p];
            py[s] = cb[N_ + p];
            pz[s] = cb[2 * N_ + p];
            mind[s] = 1e10f;
            pts[p] = make_float4(px[s], py[s], pz[s], 0.f);
        }
        __syncthreads();
        float4 p0 = pts[0];
        float lx = p0.x, ly = p0.y, lz = p0.z;

        int par = 0;
        for (int m = 1; m < M_; ++m) {
            float bv = -1.0f; int bs = 0;
#pragma unroll
            for (int s = 0; s < 16; ++s) {
                float dx = px[s] - lx;
                float dy = py[s] - ly;
                float dz = pz[s] - lz;
                float d = __builtin_fmaf(dz, dz, __builtin_fmaf(dy, dy, dx * dx));  // frozen
                float mn = fminf(mind[s], d);
                mind[s] = mn;
                if (mn > bv) { bv = mn; bs = s; }   // strict >, ascending s: min idx in thread
            }
            int bi = tid + bs * 512;
            unsigned kd = __float_as_uint(bv);
            unsigned md = wave_reduce_umax(kd);
            unsigned cand = (kd == md) ? (unsigned)bi : 0xffffffffu;
            unsigned mi = wave_reduce_umin(cand);
            if (lane == 0)
                kbuf[par][wid] = ((unsigned long long)md << 32) |
                                 (unsigned long long)(0xffffffffu - mi);   // u64 max == lex rule
            __syncthreads();
            // vectorized tree max over 8 wave keys (exact; keys distinct across waves)
            const unsigned long long* kb = kbuf[par];
            ulonglong2 q0 = *(const ulonglong2*)&kb[0];
            ulonglong2 q1 = *(const ulonglong2*)&kb[2];
            ulonglong2 q2 = *(const ulonglong2*)&kb[4];
            ulonglong2 q3 = *(const ulonglong2*)&kb[6];
            unsigned long long a0 = q0.x > q0.y ? q0.x : q0.y;
            unsigned long long a1 = q1.x > q1.y ? q1.x : q1.y;
            unsigned long long a2 = q2.x > q2.y ? q2.x : q2.y;
            unsigned long long a3 = q3.x > q3.y ? q3.x : q3.y;
            unsigned long long b01 = a0 > a1 ? a0 : a1;
            unsigned long long b23 = a2 > a3 ? a2 : a3;
            unsigned long long best = b01 > b23 ? b01 : b23;
            int widx = (int)(0xffffffffu - (unsigned)(best & 0xffffffffull));
            widx = ((unsigned)widx < (unsigned)N_) ? widx : 0;             // fault guard
            float4 wp = pts[widx];                                         // LDS broadcast
            lx = wp.x; ly = wp.y; lz = wp.z;
            if (tid == 0) wlist[m] = widx;
            par ^= 1;
        }

        // epilogue: 4 winners per thread, read wlist + pts after final barrier
        __syncthreads();
        for (int mm = tid; mm < M_; mm += 512) {
            int wi = (mm == 0) ? 0 : wlist[mm];
            wi = ((unsigned)wi < (unsigned)N_) ? wi : 0;                   // fault guard
            float4 wp = pts[wi];
            ((float4*)fpts)[b * M_ + mm] = make_float4(wp.x, wp.y, wp.z, 0.f);
            out_fps[(size_t)b * 3 * M_ + 0 * M_ + mm] = wp.x;
            out_fps[(size_t)b * 3 * M_ + 1 * M_ + mm] = wp.y;
            out_fps[(size_t)b * 3 * M_ + 2 * M_ + mm] = wp.z;
        }
    } else {
        // ================= GEMM: hp[b][n][o] = sum_c x[b][c][n] * W[o][c] ===
        const int gb = blockIdx.x - B_;
        // zero the (b,n) gather-count histogram: 2048 blocks x 32 ints = 65536
        if (tid < 32) counts[gb * 32 + tid] = 0;

        const int b = gb >> 8;                    // 256 tiles per batch
        const int rem = gb & 255;
        const int n0 = (rem >> 2) * 128;
        const int o0 = (rem & 3) * 64;
        const int tn = (tid & 31) * 4;            // 0..124
        const int to = (tid >> 5) * 4;            // 0..60
        const float* xg = x + (size_t)b * CIN_ * N_;
        float (*Xs)[128] = sm.g.Xs;
        float (*Wt)[68] = sm.g.Wt;

        float acc[4][4] = {};
        for (int kk = 0; kk < CIN_; kk += 64) {
#pragma unroll
            for (int i = 0; i < 16; ++i) {        // 8192 elems of Xs
                int e = tid + 512 * i;
                int r = e >> 7, q = e & 127;
                Xs[r][q] = xg[(size_t)(kk + r) * N_ + n0 + q];
            }
#pragma unroll
            for (int i = 0; i < 8; ++i) {         // 4096 elems of Wt
                int e = tid + 512 * i;
                int r = e >> 6, q = e & 63;
                Wt[q][r] = W[(size_t)(o0 + r) * CIN_ + kk + q];
            }
            __syncthreads();
#pragma unroll 8
            for (int c = 0; c < 64; ++c) {
                float4 a = *(const float4*)&Xs[c][tn];
                float4 bb = *(const float4*)&Wt[c][to];
                float av[4] = {a.x, a.y, a.z, a.w};
                float bv[4] = {bb.x, bb.y, bb.z, bb.w};
#pragma unroll
                for (int j = 0; j < 4; ++j)
#pragma unroll
                    for (int l = 0; l < 4; ++l)
                        acc[j][l] += av[j] * bv[l];
            }
            __syncthreads();
        }
#pragma unroll
        for (int j = 0; j < 4; ++j) {
            float4 v = make_float4(acc[j][0], acc[j][1], acc[j][2], acc[j][3]);
            *(float4*)&hp[((size_t)b * N_ + n0 + tn + j) * COUT_ + o0 + to] = v;
        }
    }
}

// ---------------------------------------------------------------------------
// kNN: ONE WAVE per (b,m) row (R1 structure — empirically bit-equivalent to
// brute force via R1==R3 output equality). Top-16 as lane-distributed sorted
// list (lane r = rank r, lanes 16..63 sentinels); fast path = dist + 1 ballot
// per 64 candidates; inserts are wave-uniform shuffles. Distances use the
// FROZEN fmaf op order. NEW: epilogue also bumps the (b,n) gather-count
// histogram (same clamped index as the knn write) for the streamed BN stats.
// ---------------------------------------------------------------------------
__global__ __launch_bounds__(256) void knn_kernel(const float* __restrict__ coords,
                                                  const float* __restrict__ fpts,
                                                  int* __restrict__ knn,
                                                  int* __restrict__ counts) {
#pragma clang fp contract(off)
    const int bidx = blockIdx.x;
    const int b = bidx >> 9;                  // 512 blocks per batch
    const int mg = bidx & 511;
    const int tid = threadIdx.x;
    const int lane = tid & 63;
    const int w = tid >> 6;
    const int m = mg * 4 + w;
    const int row = b * M_ + m;
    const float* cb = coords + (size_t)b * 3 * N_;

    __shared__ float4 tile[1024];

    float4 f = ((const float4*)fpts)[row];
    const float fx = f.x, fy = f.y, fz = f.z;
    const float sf = __builtin_fmaf(fz, fz, __builtin_fmaf(fy, fy, fx * fx));  // frozen

    float ed = INFINITY; int ei = 0x7fffffff;     // distributed list entry
    float tau_d = INFINITY; int tau_i = 0x7fffffff;

    for (int t = 0; t < 8; ++t) {
        const int base = t * 1024;
#pragma unroll
        for (int j = 0; j < 4; ++j) {
            int idx = tid + 256 * j;
            int n = base + idx;
            float gx = cb[n], gy = cb[N_ + n], gz = cb[2 * N_ + n];
            float sp = __builtin_fmaf(gz, gz, __builtin_fmaf(gy, gy, gx * gx)); // frozen
            tile[idx] = make_float4(gx, gy, gz, sp);
        }
        __syncthreads();
        for (int s = 0; s < 16; ++s) {
            int l = s * 64 + lane;
            float4 p = tile[l];
            int n = base + l;
            float dot = __builtin_fmaf(fz, p.z, __builtin_fmaf(fy, p.y, fx * p.x)); // frozen
            float d = (sf + p.w) - 2.0f * dot;                                      // frozen
            bool q = (d < tau_d) || (d == tau_d && n < tau_i);
            unsigned long long bal = __ballot(q);
            while (bal) {
                int lb = __ffsll(bal) - 1;
                bal &= bal - 1;
                float dv = __shfl(d, lb);
                int   iv = __shfl(n, lb);
                if ((dv < tau_d) || (dv == tau_d && iv < tau_i)) {
                    float pud = __shfl_up(ed, 1);
                    int   pui = __shfl_up(ei, 1);
                    bool cs = (dv < ed) || (dv == ed && iv < ei);
                    bool cp = (lane != 0) && ((dv < pud) || (dv == pud && iv < pui));
                    ed = cs ? (cp ? pud : dv) : ed;
                    ei = cs ? (cp ? pui : iv) : ei;
                    tau_d = __shfl(ed, 15);
                    tau_i = __shfl(ei, 15);
                }
            }
        }
        __syncthreads();
    }
    if (lane < K_) {
        int v = ei;
        v = ((unsigned)v < (unsigned)N_) ? v : 0;          // fault guard
        knn[(size_t)row * K_ + lane] = v;
        atomicAdd(&counts[b * N_ + v], 1);                 // histogram for BN stats
    }
}

// ---------------------------------------------------------------------------
// BN stats stage 1, HISTOGRAM FORM: sum over gathered rows == sum over unique
// (b,n) of cnt * hp[b][n][o]. Streams hp once (64MB; cnt==0 rows skipped by a
// wave-uniform branch) instead of the old 268MB gather. cnt*h is EXACT in f64
// (24-bit mantissa x cnt<=2^18 <= 42 bits); only the f64 summation order
// changes vs the gather form -> scale/bias perturbed ~1e-13 rel, far inside
// tolerance. Deterministic (fixed ascending-row order per partial).
// ---------------------------------------------------------------------------
__global__ __launch_bounds__(256) void stats_partial_kernel(const float* __restrict__ hp,
                                                            const int* __restrict__ counts,
                                                            double* __restrict__ partial,
                                                            double* __restrict__ partial2) {
    const int o = threadIdx.x;
    const int base = blockIdx.x * 256;             // 256 blocks x 256 rows = 65536 (b,n)
    double s = 0.0, s2 = 0.0;
    for (int r = 0; r < 256; ++r) {
        int g = base + r;                          // g = b*N + n  (hp row index)
        int cnt = counts[g];                       // scalar across the block
        if (cnt) {                                 // wave-uniform skip
            double h = (double)hp[(size_t)g * COUT_ + o];
            double c = (double)cnt;
            double ch = c * h;                     // exact
            s += ch;
            s2 += ch * h;
        }
    }
    partial[(size_t)blockIdx.x * 256 + o] = s;
    partial2[(size_t)blockIdx.x * 256 + o] = s2;
}

__global__ void bn_final_kernel(const double* __restrict__ partial,
                                const double* __restrict__ partial2,
                                const float* __restrict__ gamma,
                                const float* __restrict__ beta,
                                float* __restrict__ scale,
                                float* __restrict__ bias) {
    int o = threadIdx.x;
    double s = 0.0, s2 = 0.0;
    for (int j = 0; j < 256; ++j) {
        s += partial[(size_t)j * 256 + o];
        s2 += partial2[(size_t)j * 256 + o];
    }
    const double inv = 1.0 / (double)(B_ * M_ * K_);
    double mean = s * inv;
    double var = s2 * inv - mean * mean;
    if (var < 0.0) var = 0.0;
    double r = 1.0 / sqrt(var + 1e-5);
    double g = (double)gamma[o];
    scale[o] = (float)(r * g);
    bias[o] = (float)((double)beta[o] - mean * r * g);
}

// ---------------------------------------------------------------------------
// Finalize: y[b][o][m] = relu( max_k ( hp[gather] * scale + bias ) ) (unchanged)
// ---------------------------------------------------------------------------
__global__ __launch_bounds__(256) void finalize_kernel(const float* __restrict__ hp,
                                                       const int* __restrict__ knn,
                                                       const float* __restrict__ scale,
                                                       const float* __restrict__ bias,
                                                       float* __restrict__ y) {
    const int b = blockIdx.x >> 6;
    const int m0 = (blockIdx.x & 63) * 32;
    const int tid = threadIdx.x;
    __shared__ int kidx[512];
    __shared__ float tile[32][257];

    for (int e = tid; e < 512; e += 256) {
        int n = knn[(b * M_ + m0 + (e >> 4)) * K_ + (e & 15)];
        kidx[e] = ((unsigned)n < (unsigned)N_) ? n : 0;   // fault guard
    }
    __syncthreads();

    const float s = scale[tid];
    const float t = bias[tid];
    const float* hb = hp + (size_t)b * N_ * COUT_;
    for (int mm = 0; mm < 32; ++mm) {
        float v = -INFINITY;
#pragma unroll
        for (int k = 0; k < K_; ++k) {
            int n = kidx[mm * 16 + k];
            float h = hb[(size_t)n * COUT_ + tid];
            v = fmaxf(v, h * s + t);
        }
        v = fmaxf(v, 0.0f);
        tile[mm][tid] = v;
    }
    __syncthreads();
#pragma unroll
    for (int r = 0; r < 32; ++r) {
        int o2 = r * 8 + (tid >> 5);
        int mm = tid & 31;
        y[((size_t)b * COUT_ + o2) * M_ + m0 + mm] = tile[mm][o2];
    }
}

__global__ void sentinel_kernel(float* out, float v) { out[0] = v; }

// ---------------------------------------------------------------------------
extern "C" void kernel_launch(void* const* d_in, const int* in_sizes, int n_in,
                              void* d_out, int out_size, void* d_ws, size_t ws_size,
                              hipStream_t stream) {
    const float* x = (const float*)d_in[0];
    const float* coords = (const float*)d_in[1];
    const float* W = (const float*)d_in[2];
    const float* gamma = (const float*)d_in[3];
    const float* beta = (const float*)d_in[4];
    float* y = (float*)d_out;
    float* out_fps = y + (size_t)B_ * COUT_ * M_;     // fps_coords after y (f32)

    if (n_in != 5 ||
        in_sizes[0] != B_ * CIN_ * N_ ||
        in_sizes[1] != B_ * 3 * N_ ||
        in_sizes[2] != COUT_ * CIN_ ||
        in_sizes[3] != COUT_ || in_sizes[4] != COUT_ ||
        out_size != B_ * COUT_ * M_ + B_ * 3 * M_) {
        sentinel_kernel<<<1, 1, 0, stream>>>(y, -2.0e6f);
        return;
    }

    const size_t HP_BYTES = (size_t)B_ * N_ * COUT_ * 4;          // 64 MB
    const size_t FPTS_BYTES = (size_t)B_ * M_ * 16;               // 256 KB
    const size_t KNN_BYTES = (size_t)B_ * M_ * K_ * 4;            // 1 MB
    const size_t PART_BYTES = (size_t)256 * 256 * 8;              // 512 KB
    const size_t CNT_BYTES = (size_t)B_ * N_ * 4;                 // 256 KB
    const size_t NEED = HP_BYTES + FPTS_BYTES + KNN_BYTES + 2 * PART_BYTES + CNT_BYTES + 8192;
    if (ws_size < NEED) {
        sentinel_kernel<<<1, 1, 0, stream>>>(y, -1.0e6f);
        return;
    }
    char* ws = (char*)d_ws;
    float* hp = (float*)ws;
    float* fpts = (float*)(ws + HP_BYTES);
    int* knn = (int*)(ws + HP_BYTES + FPTS_BYTES);
    double* partial = (double*)(ws + HP_BYTES + FPTS_BYTES + KNN_BYTES);
    double* partial2 = (double*)(ws + HP_BYTES + FPTS_BYTES + KNN_BYTES + PART_BYTES);
    int* counts = (int*)(ws + HP_BYTES + FPTS_BYTES + KNN_BYTES + 2 * PART_BYTES);
    float* scale = (float*)(ws + HP_BYTES + FPTS_BYTES + KNN_BYTES + 2 * PART_BYTES + CNT_BYTES);
    float* bias = scale + 256;

    fps_gemm_kernel<<<B_ + GEMM_BLOCKS, 512, 0, stream>>>(coords, x, W, fpts, out_fps, hp, counts);
    knn_kernel<<<B_ * 512, 256, 0, stream>>>(coords, fpts, knn, counts);
    stats_partial_kernel<<<256, 256, 0, stream>>>(hp, counts, partial, partial2);
    bn_final_kernel<<<1, 256, 0, stream>>>(partial, partial2, gamma, beta, scale, bias);
    finalize_kernel<<<512, 256, 0, stream>>>(hp, knn, scale, bias, y);
}

// Round 7
// 1762.544 us; speedup vs baseline: 1.0778x; 1.0778x over previous
//
#include <hip/hip_runtime.h>
#include <math.h>

#define B_ 8
#define CIN_ 128
#define COUT_ 256
#define N_ 8192
#define M_ 2048
#define K_ 16

#define WORKERS 240          // non-FPS blocks in the mega kernel
#define NTILE 2048           // gemm: 8 b x 256 tiles (128n x 64o)
#define NGROUP 2048          // knn: 8 b x 256 groups of 8 rows

// ---------------------------------------------------------------------------
// DPP wave reductions (row_shr 1/2/4/8 + row_bcast 15/31): VALU-latency only.
// (R1/v4 exact form — measured best fps; R2/R3 restructures both lost.)
// ---------------------------------------------------------------------------
__device__ __forceinline__ unsigned umax2(unsigned a, unsigned b) { return a > b ? a : b; }
__device__ __forceinline__ unsigned umin2(unsigned a, unsigned b) { return a < b ? a : b; }

__device__ __forceinline__ unsigned wave_reduce_umax(unsigned v) {
    v = umax2(v, (unsigned)__builtin_amdgcn_update_dpp(0, (int)v, 0x111, 0xf, 0xf, false));
    v = umax2(v, (unsigned)__builtin_amdgcn_update_dpp(0, (int)v, 0x112, 0xf, 0xf, false));
    v = umax2(v, (unsigned)__builtin_amdgcn_update_dpp(0, (int)v, 0x114, 0xf, 0xf, false));
    v = umax2(v, (unsigned)__builtin_amdgcn_update_dpp(0, (int)v, 0x118, 0xf, 0xf, false));
    v = umax2(v, (unsigned)__builtin_amdgcn_update_dpp(0, (int)v, 0x142, 0xf, 0xf, false));
    v = umax2(v, (unsigned)__builtin_amdgcn_update_dpp(0, (int)v, 0x143, 0xf, 0xf, false));
    return (unsigned)__builtin_amdgcn_readlane((int)v, 63);
}
__device__ __forceinline__ unsigned wave_reduce_umin(unsigned v) {
    v = umin2(v, (unsigned)__builtin_amdgcn_update_dpp(-1, (int)v, 0x111, 0xf, 0xf, false));
    v = umin2(v, (unsigned)__builtin_amdgcn_update_dpp(-1, (int)v, 0x112, 0xf, 0xf, false));
    v = umin2(v, (unsigned)__builtin_amdgcn_update_dpp(-1, (int)v, 0x114, 0xf, 0xf, false));
    v = umin2(v, (unsigned)__builtin_amdgcn_update_dpp(-1, (int)v, 0x118, 0xf, 0xf, false));
    v = umin2(v, (unsigned)__builtin_amdgcn_update_dpp(-1, (int)v, 0x142, 0xf, 0xf, false));
    v = umin2(v, (unsigned)__builtin_amdgcn_update_dpp(-1, (int)v, 0x143, 0xf, 0xf, false));
    return (unsigned)__builtin_amdgcn_readlane((int)v, 63);
}

// ---------------------------------------------------------------------------
// MEGA kernel (producer-consumer):
//   blocks 0..7    : FPS (R1/v4 verbatim) + progressive winner publication
//                    via relaxed agent-scope atomic store to wflag[b*M+m].
//                    The u32 IS the payload (knn re-derives coords from the
//                    read-only coords array -> bit-identical) so no fence.
//   blocks 8..247  : GEMM tiles (grid-stride, ~50us), then knn groups in
//                    ascending-m order, spin-waiting on wflag (s_sleep
//                    backoff). Frontier trails FPS; last group done ~us
//                    after FPS ends.
// Deadlock-safe WITHOUT cooperative launch: 248 blocks x 139.4KB LDS =
// 1 block/CU <= 256 CUs -> all blocks co-resident by CAPACITY, regardless
// of dispatch order (G16-safe: no ordering assumption, only capacity).
// wflag preset to 0xFF by hipMemsetAsync (stream-ordered); winner idx <8192
// never collides. FPS decision math FROZEN; knn candidate order & insert
// math FROZEN -> knn indices bit-identical; GEMM accumulation order
// unchanged -> hp bit-identical.
// ---------------------------------------------------------------------------
__global__ __launch_bounds__(512) void mega_kernel(const float* __restrict__ coords,
                                                   const float* __restrict__ x,
                                                   const float* __restrict__ W,
                                                   unsigned* __restrict__ wflag,
                                                   float* __restrict__ out_fps,
                                                   float* __restrict__ hp,
                                                   int* __restrict__ knn,
                                                   int* __restrict__ counts) {
    __shared__ union {
        struct {
            float4 pts[N_];                      // 128 KiB
            unsigned long long kbuf[2][8];
            int wlist[M_];                       // 8 KiB
        } f;
        struct {
            float Xs[64][128];                   // 32 KiB
            float Wt[64][68];                    // 17 KiB
        } g;
        struct {
            float4 tile[1024];                   // 16 KiB
        } k;
    } sm;

    const int tid = threadIdx.x;
    const int lane = tid & 63;
    const int w = tid >> 6;                      // wave id 0..7

    if (blockIdx.x < B_) {
        // ================= FPS (R1/v4 exact + winner publication) ==========
#pragma clang fp contract(off)
        const int b = blockIdx.x;
        const float* cb = coords + (size_t)b * 3 * N_;
        float4* pts = sm.f.pts;
        unsigned long long (*kbuf)[8] = sm.f.kbuf;
        int* wlist = sm.f.wlist;

        float px[16], py[16], pz[16], mind[16];
#pragma unroll
        for (int s = 0; s < 16; ++s) {
            int p = tid + s * 512;
            px[s] = cb[p];
            py[s] = cb[N_ + p];
            pz[s] = cb[2 * N_ + p];
            mind[s] = 1e10f;
            pts[p] = make_float4(px[s], py[s], pz[s], 0.f);
        }
        if (tid == 0)
            __hip_atomic_store(&wflag[(size_t)b * M_], 0u,
                               __ATOMIC_RELAXED, __HIP_MEMORY_SCOPE_AGENT);
        __syncthreads();
        float4 p0 = pts[0];
        float lx = p0.x, ly = p0.y, lz = p0.z;

        int par = 0;
        for (int m = 1; m < M_; ++m) {
            float bv = -1.0f; int bs = 0;
#pragma unroll
            for (int s = 0; s < 16; ++s) {
                float dx = px[s] - lx;
                float dy = py[s] - ly;
                float dz = pz[s] - lz;
                float d = __builtin_fmaf(dz, dz, __builtin_fmaf(dy, dy, dx * dx));  // frozen
                float mn = fminf(mind[s], d);
                mind[s] = mn;
                if (mn > bv) { bv = mn; bs = s; }   // strict >, ascending s: min idx in thread
            }
            int bi = tid + bs * 512;
            unsigned kd = __float_as_uint(bv);
            unsigned md = wave_reduce_umax(kd);
            unsigned cand = (kd == md) ? (unsigned)bi : 0xffffffffu;
            unsigned mi = wave_reduce_umin(cand);
            if (lane == 0)
                kbuf[par][w] = ((unsigned long long)md << 32) |
                               (unsigned long long)(0xffffffffu - mi);   // u64 max == lex rule
            __syncthreads();
            // vectorized tree max over 8 wave keys (exact; keys distinct across waves)
            const unsigned long long* kb = kbuf[par];
            ulonglong2 q0 = *(const ulonglong2*)&kb[0];
            ulonglong2 q1 = *(const ulonglong2*)&kb[2];
            ulonglong2 q2 = *(const ulonglong2*)&kb[4];
            ulonglong2 q3 = *(const ulonglong2*)&kb[6];
            unsigned long long a0 = q0.x > q0.y ? q0.x : q0.y;
            unsigned long long a1 = q1.x > q1.y ? q1.x : q1.y;
            unsigned long long a2 = q2.x > q2.y ? q2.x : q2.y;
            unsigned long long a3 = q3.x > q3.y ? q3.x : q3.y;
            unsigned long long b01 = a0 > a1 ? a0 : a1;
            unsigned long long b23 = a2 > a3 ? a2 : a3;
            unsigned long long best = b01 > b23 ? b01 : b23;
            int widx = (int)(0xffffffffu - (unsigned)(best & 0xffffffffull));
            widx = ((unsigned)widx < (unsigned)N_) ? widx : 0;             // fault guard
            float4 wp = pts[widx];                                         // LDS broadcast
            lx = wp.x; ly = wp.y; lz = wp.z;
            if (tid == 0) {
                wlist[m] = widx;
                __hip_atomic_store(&wflag[(size_t)b * M_ + m], (unsigned)widx,
                                   __ATOMIC_RELAXED, __HIP_MEMORY_SCOPE_AGENT);
            }
            par ^= 1;
        }

        // epilogue: out_fps only (fpts buffer eliminated; knn reads coords)
        __syncthreads();
        for (int mm = tid; mm < M_; mm += 512) {
            int wi = (mm == 0) ? 0 : wlist[mm];
            wi = ((unsigned)wi < (unsigned)N_) ? wi : 0;                   // fault guard
            float4 wp = pts[wi];
            out_fps[(size_t)b * 3 * M_ + 0 * M_ + mm] = wp.x;
            out_fps[(size_t)b * 3 * M_ + 1 * M_ + mm] = wp.y;
            out_fps[(size_t)b * 3 * M_ + 2 * M_ + mm] = wp.z;
        }
    } else {
        const int wkr = blockIdx.x - B_;          // 0..239

        // ================= GEMM: hp[b][n][o] = sum_c x[b][c][n]*W[o][c] ====
        float (*Xs)[128] = sm.g.Xs;
        float (*Wt)[68] = sm.g.Wt;
        for (int t = wkr; t < NTILE; t += WORKERS) {
            const int b = t >> 8;                 // 256 tiles per batch
            const int rem = t & 255;
            const int n0 = (rem >> 2) * 128;
            const int o0 = (rem & 3) * 64;
            const int tn = (tid & 31) * 4;        // 0..124
            const int to = (tid >> 5) * 4;        // 0..60
            const float* xg = x + (size_t)b * CIN_ * N_;

            float acc[4][4] = {};
            for (int kk = 0; kk < CIN_; kk += 64) {
#pragma unroll
                for (int i = 0; i < 16; ++i) {    // 8192 elems of Xs
                    int e = tid + 512 * i;
                    int r = e >> 7, q = e & 127;
                    Xs[r][q] = xg[(size_t)(kk + r) * N_ + n0 + q];
                }
#pragma unroll
                for (int i = 0; i < 8; ++i) {     // 4096 elems of Wt
                    int e = tid + 512 * i;
                    int r = e >> 6, q = e & 63;
                    Wt[q][r] = W[(size_t)(o0 + r) * CIN_ + kk + q];
                }
                __syncthreads();
#pragma unroll 8
                for (int c = 0; c < 64; ++c) {
                    float4 a = *(const float4*)&Xs[c][tn];
                    float4 bb = *(const float4*)&Wt[c][to];
                    float av[4] = {a.x, a.y, a.z, a.w};
                    float bv[4] = {bb.x, bb.y, bb.z, bb.w};
#pragma unroll
                    for (int j = 0; j < 4; ++j)
#pragma unroll
                        for (int l = 0; l < 4; ++l)
                            acc[j][l] += av[j] * bv[l];
                }
                __syncthreads();
            }
#pragma unroll
            for (int j = 0; j < 4; ++j) {
                float4 v = make_float4(acc[j][0], acc[j][1], acc[j][2], acc[j][3]);
                *(float4*)&hp[((size_t)b * N_ + n0 + tn + j) * COUT_ + o0 + to] = v;
            }
        }

        // ================= kNN (progressive consumer) ======================
        // One wave per row, 8 rows per group; groups in ascending-m order so
        // the frontier trails the FPS producer. Candidate order, FROZEN fmaf
        // distances, ballot/insert math identical to R5 -> indices
        // bit-identical. (Own compound block so the fp pragma is legal.)
        {
#pragma clang fp contract(off)
            float4* tile = sm.k.tile;
            for (int g = wkr; g < NGROUP; g += WORKERS) {
                const int b = g & 7;
                const int mg = g >> 3;
                const int m = mg * 8 + w;
                const int row = b * M_ + m;
                const float* cb = coords + (size_t)b * 3 * N_;

                unsigned widx;
                while ((widx = __hip_atomic_load(&wflag[row], __ATOMIC_RELAXED,
                                                 __HIP_MEMORY_SCOPE_AGENT)) == 0xffffffffu)
                    __builtin_amdgcn_s_sleep(2);
                widx = (widx < (unsigned)N_) ? widx : 0;   // fault guard

                const float fx = cb[widx];
                const float fy = cb[N_ + widx];
                const float fz = cb[2 * N_ + widx];        // same floats as old fpts
                const float sf = __builtin_fmaf(fz, fz, __builtin_fmaf(fy, fy, fx * fx)); // frozen

                float ed = INFINITY; int ei = 0x7fffffff;  // distributed list entry
                float tau_d = INFINITY; int tau_i = 0x7fffffff;

                for (int t = 0; t < 8; ++t) {
                    const int base = t * 1024;
#pragma unroll
                    for (int j = 0; j < 2; ++j) {
                        int idx = tid + 512 * j;
                        int n = base + idx;
                        float gx = cb[n], gy = cb[N_ + n], gz = cb[2 * N_ + n];
                        float sp = __builtin_fmaf(gz, gz, __builtin_fmaf(gy, gy, gx * gx)); // frozen
                        tile[idx] = make_float4(gx, gy, gz, sp);
                    }
                    __syncthreads();
                    for (int s = 0; s < 16; ++s) {
                        int l = s * 64 + lane;
                        float4 p = tile[l];
                        int n = base + l;
                        float dot = __builtin_fmaf(fz, p.z, __builtin_fmaf(fy, p.y, fx * p.x)); // frozen
                        float d = (sf + p.w) - 2.0f * dot;                                      // frozen
                        bool q = (d < tau_d) || (d == tau_d && n < tau_i);
                        unsigned long long bal = __ballot(q);
                        while (bal) {
                            int lb = __ffsll(bal) - 1;
                            bal &= bal - 1;
                            float dv = __shfl(d, lb);
                            int   iv = __shfl(n, lb);
                            if ((dv < tau_d) || (dv == tau_d && iv < tau_i)) {
                                float pud = __shfl_up(ed, 1);
                                int   pui = __shfl_up(ei, 1);
                                bool cs = (dv < ed) || (dv == ed && iv < ei);
                                bool cp = (lane != 0) && ((dv < pud) || (dv == pud && iv < pui));
                                ed = cs ? (cp ? pud : dv) : ed;
                                ei = cs ? (cp ? pui : iv) : ei;
                                tau_d = __shfl(ed, 15);
                                tau_i = __shfl(ei, 15);
                            }
                        }
                    }
                    __syncthreads();
                }
                if (lane < K_) {
                    int v = ei;
                    v = ((unsigned)v < (unsigned)N_) ? v : 0;          // fault guard
                    knn[(size_t)row * K_ + lane] = v;
                    atomicAdd(&counts[b * N_ + v], 1);                 // histogram for BN stats
                }
            }
        }
    }
}

// ---------------------------------------------------------------------------
// BN stats stage 1, HISTOGRAM FORM (R5-verified): sum over gathered rows ==
// sum over unique (b,n) of cnt * hp[b][n][o]. cnt*h exact in f64; summation
// order deterministic.
// ---------------------------------------------------------------------------
__global__ __launch_bounds__(256) void stats_partial_kernel(const float* __restrict__ hp,
                                                            const int* __restrict__ counts,
                                                            double* __restrict__ partial,
                                                            double* __restrict__ partial2) {
    const int o = threadIdx.x;
    const int base = blockIdx.x * 256;             // 256 blocks x 256 rows = 65536 (b,n)
    double s = 0.0, s2 = 0.0;
    for (int r = 0; r < 256; ++r) {
        int g = base + r;                          // g = b*N + n  (hp row index)
        int cnt = counts[g];                       // scalar across the block
        if (cnt) {                                 // wave-uniform skip
            double h = (double)hp[(size_t)g * COUT_ + o];
            double c = (double)cnt;
            double ch = c * h;                     // exact
            s += ch;
            s2 += ch * h;
        }
    }
    partial[(size_t)blockIdx.x * 256 + o] = s;
    partial2[(size_t)blockIdx.x * 256 + o] = s2;
}

__global__ void bn_final_kernel(const double* __restrict__ partial,
                                const double* __restrict__ partial2,
                                const float* __restrict__ gamma,
                                const float* __restrict__ beta,
                                float* __restrict__ scale,
                                float* __restrict__ bias) {
    int o = threadIdx.x;
    double s = 0.0, s2 = 0.0;
    for (int j = 0; j < 256; ++j) {
        s += partial[(size_t)j * 256 + o];
        s2 += partial2[(size_t)j * 256 + o];
    }
    const double inv = 1.0 / (double)(B_ * M_ * K_);
    double mean = s * inv;
    double var = s2 * inv - mean * mean;
    if (var < 0.0) var = 0.0;
    double r = 1.0 / sqrt(var + 1e-5);
    double g = (double)gamma[o];
    scale[o] = (float)(r * g);
    bias[o] = (float)((double)beta[o] - mean * r * g);
}

// ---------------------------------------------------------------------------
// Finalize: y[b][o][m] = relu( max_k ( hp[gather] * scale + bias ) ) (unchanged)
// ---------------------------------------------------------------------------
__global__ __launch_bounds__(256) void finalize_kernel(const float* __restrict__ hp,
                                                       const int* __restrict__ knn,
                                                       const float* __restrict__ scale,
                                                       const float* __restrict__ bias,
                                                       float* __restrict__ y) {
    const int b = blockIdx.x >> 6;
    const int m0 = (blockIdx.x & 63) * 32;
    const int tid = threadIdx.x;
    __shared__ int kidx[512];
    __shared__ float tile[32][257];

    for (int e = tid; e < 512; e += 256) {
        int n = knn[(b * M_ + m0 + (e >> 4)) * K_ + (e & 15)];
        kidx[e] = ((unsigned)n < (unsigned)N_) ? n : 0;   // fault guard
    }
    __syncthreads();

    const float s = scale[tid];
    const float t = bias[tid];
    const float* hb = hp + (size_t)b * N_ * COUT_;
    for (int mm = 0; mm < 32; ++mm) {
        float v = -INFINITY;
#pragma unroll
        for (int k = 0; k < K_; ++k) {
            int n = kidx[mm * 16 + k];
            float h = hb[(size_t)n * COUT_ + tid];
            v = fmaxf(v, h * s + t);
        }
        v = fmaxf(v, 0.0f);
        tile[mm][tid] = v;
    }
    __syncthreads();
#pragma unroll
    for (int r = 0; r < 32; ++r) {
        int o2 = r * 8 + (tid >> 5);
        int mm = tid & 31;
        y[((size_t)b * COUT_ + o2) * M_ + m0 + mm] = tile[mm][o2];
    }
}

__global__ void sentinel_kernel(float* out, float v) { out[0] = v; }

// ---------------------------------------------------------------------------
extern "C" void kernel_launch(void* const* d_in, const int* in_sizes, int n_in,
                              void* d_out, int out_size, void* d_ws, size_t ws_size,
                              hipStream_t stream) {
    const float* x = (const float*)d_in[0];
    const float* coords = (const float*)d_in[1];
    const float* W = (const float*)d_in[2];
    const float* gamma = (const float*)d_in[3];
    const float* beta = (const float*)d_in[4];
    float* y = (float*)d_out;
    float* out_fps = y + (size_t)B_ * COUT_ * M_;     // fps_coords after y (f32)

    if (n_in != 5 ||
        in_sizes[0] != B_ * CIN_ * N_ ||
        in_sizes[1] != B_ * 3 * N_ ||
        in_sizes[2] != COUT_ * CIN_ ||
        in_sizes[3] != COUT_ || in_sizes[4] != COUT_ ||
        out_size != B_ * COUT_ * M_ + B_ * 3 * M_) {
        sentinel_kernel<<<1, 1, 0, stream>>>(y, -2.0e6f);
        return;
    }

    const size_t HP_BYTES = (size_t)B_ * N_ * COUT_ * 4;          // 64 MB
    const size_t KNN_BYTES = (size_t)B_ * M_ * K_ * 4;            // 1 MB
    const size_t PART_BYTES = (size_t)256 * 256 * 8;              // 512 KB
    const size_t CNT_BYTES = (size_t)B_ * N_ * 4;                 // 256 KB
    const size_t WFLAG_BYTES = (size_t)B_ * M_ * 4;               // 64 KB
    const size_t NEED = HP_BYTES + KNN_BYTES + 2 * PART_BYTES + CNT_BYTES + WFLAG_BYTES + 8192;
    if (ws_size < NEED) {
        sentinel_kernel<<<1, 1, 0, stream>>>(y, -1.0e6f);
        return;
    }
    char* ws = (char*)d_ws;
    float* hp = (float*)ws;
    int* knn = (int*)(ws + HP_BYTES);
    double* partial = (double*)(ws + HP_BYTES + KNN_BYTES);
    double* partial2 = (double*)(ws + HP_BYTES + KNN_BYTES + PART_BYTES);
    int* counts = (int*)(ws + HP_BYTES + KNN_BYTES + 2 * PART_BYTES);
    unsigned* wflag = (unsigned*)(ws + HP_BYTES + KNN_BYTES + 2 * PART_BYTES + CNT_BYTES);
    float* scale = (float*)(ws + HP_BYTES + KNN_BYTES + 2 * PART_BYTES + CNT_BYTES + WFLAG_BYTES);
    float* bias = scale + 256;

    (void)hipMemsetAsync(counts, 0, CNT_BYTES, stream);            // histogram zero
    (void)hipMemsetAsync(wflag, 0xFF, WFLAG_BYTES, stream);        // winner flags = empty

    mega_kernel<<<B_ + WORKERS, 512, 0, stream>>>(coords, x, W, wflag, out_fps,
                                                  hp, knn, counts);
    stats_partial_kernel<<<256, 256, 0, stream>>>(hp, counts, partial, partial2);
    bn_final_kernel<<<1, 256, 0, stream>>>(partial, partial2, gamma, beta, scale, bias);
    finalize_kernel<<<512, 256, 0, stream>>>(hp, knn, scale, bias, y);
}

// Round 9
// 1712.186 us; speedup vs baseline: 1.1095x; 1.0294x over previous
//
#include <hip/hip_runtime.h>
#include <math.h>

#define B_ 8
#define CIN_ 128
#define COUT_ 256
#define N_ 8192
#define M_ 2048
#define K_ 16

#define WORKERS 240          // non-FPS blocks in the mega kernel
#define NTILE 2048           // gemm: 8 b x 256 tiles (128n x 64o)
#define NGROUP 2048          // knn: 8 b x 256 groups of 8 rows

// ---------------------------------------------------------------------------
// DPP wave reductions (row_shr 1/2/4/8 + row_bcast 15/31): VALU-latency only.
// (R1/v4 exact form — measured best fps; R2/R3 restructures both lost.)
// ---------------------------------------------------------------------------
__device__ __forceinline__ unsigned umax2(unsigned a, unsigned b) { return a > b ? a : b; }
__device__ __forceinline__ unsigned umin2(unsigned a, unsigned b) { return a < b ? a : b; }

__device__ __forceinline__ unsigned wave_reduce_umax(unsigned v) {
    v = umax2(v, (unsigned)__builtin_amdgcn_update_dpp(0, (int)v, 0x111, 0xf, 0xf, false));
    v = umax2(v, (unsigned)__builtin_amdgcn_update_dpp(0, (int)v, 0x112, 0xf, 0xf, false));
    v = umax2(v, (unsigned)__builtin_amdgcn_update_dpp(0, (int)v, 0x114, 0xf, 0xf, false));
    v = umax2(v, (unsigned)__builtin_amdgcn_update_dpp(0, (int)v, 0x118, 0xf, 0xf, false));
    v = umax2(v, (unsigned)__builtin_amdgcn_update_dpp(0, (int)v, 0x142, 0xf, 0xf, false));
    v = umax2(v, (unsigned)__builtin_amdgcn_update_dpp(0, (int)v, 0x143, 0xf, 0xf, false));
    return (unsigned)__builtin_amdgcn_readlane((int)v, 63);
}
__device__ __forceinline__ unsigned wave_reduce_umin(unsigned v) {
    v = umin2(v, (unsigned)__builtin_amdgcn_update_dpp(-1, (int)v, 0x111, 0xf, 0xf, false));
    v = umin2(v, (unsigned)__builtin_amdgcn_update_dpp(-1, (int)v, 0x112, 0xf, 0xf, false));
    v = umin2(v, (unsigned)__builtin_amdgcn_update_dpp(-1, (int)v, 0x114, 0xf, 0xf, false));
    v = umin2(v, (unsigned)__builtin_amdgcn_update_dpp(-1, (int)v, 0x118, 0xf, 0xf, false));
    v = umin2(v, (unsigned)__builtin_amdgcn_update_dpp(-1, (int)v, 0x142, 0xf, 0xf, false));
    v = umin2(v, (unsigned)__builtin_amdgcn_update_dpp(-1, (int)v, 0x143, 0xf, 0xf, false));
    return (unsigned)__builtin_amdgcn_readlane((int)v, 63);
}

// ---------------------------------------------------------------------------
// MEGA kernel (producer-consumer, R7 structure + folded BN stats):
//   blocks 0..7    : FPS (R1/v4 verbatim) + progressive winner publication.
//   blocks 8..247  : GEMM tiles -> device-scope release/acquire barrier
//                    (all 240 workers co-resident by LDS capacity, R7-verified
//                    spin-wait) -> knn groups ascending-m, spin on wflag;
//                    after each row, gather its 16 hp rows and accumulate
//                    per-o f64 sums in registers (hidden: workers idle-spin
//                    under FPS otherwise). Block partials to fixed slots
//                    (no atomics, deterministic).
// FPS decision math FROZEN; knn candidate order & insert math FROZEN ->
// indices bit-identical; GEMM accumulation order unchanged -> hp
// bit-identical. BN sums: gather semantics (same as pre-R5), f64 grouping
// differs only (~1e-13 rel on scale/bias).
// ---------------------------------------------------------------------------
__global__ __launch_bounds__(512) void mega_kernel(const float* __restrict__ coords,
                                                   const float* __restrict__ x,
                                                   const float* __restrict__ W,
                                                   unsigned* __restrict__ wflag,
                                                   float* __restrict__ out_fps,
                                                   float* __restrict__ hp,
                                                   int* __restrict__ knn,
                                                   double* __restrict__ partial,
                                                   int* __restrict__ gbar) {
    __shared__ union {
        struct {
            float4 pts[N_];                      // 128 KiB
            unsigned long long kbuf[2][8];
            int wlist[M_];                       // 8 KiB
        } f;
        struct {
            float Xs[64][128];                   // 32 KiB
            float Wt[64][68];                    // 17 KiB
        } g;
        struct {
            float4 tile[1024];                   // 16 KiB
            double wacc[8][512];                 // 32 KiB (per-wave partials)
        } k;
    } sm;

    const int tid = threadIdx.x;
    const int lane = tid & 63;
    const int w = tid >> 6;                      // wave id 0..7

    if (blockIdx.x < B_) {
        // ================= FPS (R1/v4 exact + winner publication) ==========
#pragma clang fp contract(off)
        const int b = blockIdx.x;
        const float* cb = coords + (size_t)b * 3 * N_;
        float4* pts = sm.f.pts;
        unsigned long long (*kbuf)[8] = sm.f.kbuf;
        int* wlist = sm.f.wlist;

        float px[16], py[16], pz[16], mind[16];
#pragma unroll
        for (int s = 0; s < 16; ++s) {
            int p = tid + s * 512;
            px[s] = cb[p];
            py[s] = cb[N_ + p];
            pz[s] = cb[2 * N_ + p];
            mind[s] = 1e10f;
            pts[p] = make_float4(px[s], py[s], pz[s], 0.f);
        }
        if (tid == 0)
            __hip_atomic_store(&wflag[(size_t)b * M_], 0u,
                               __ATOMIC_RELAXED, __HIP_MEMORY_SCOPE_AGENT);
        __syncthreads();
        float4 p0 = pts[0];
        float lx = p0.x, ly = p0.y, lz = p0.z;

        int par = 0;
        for (int m = 1; m < M_; ++m) {
            float bv = -1.0f; int bs = 0;
#pragma unroll
            for (int s = 0; s < 16; ++s) {
                float dx = px[s] - lx;
                float dy = py[s] - ly;
                float dz = pz[s] - lz;
                float d = __builtin_fmaf(dz, dz, __builtin_fmaf(dy, dy, dx * dx));  // frozen
                float mn = fminf(mind[s], d);
                mind[s] = mn;
                if (mn > bv) { bv = mn; bs = s; }   // strict >, ascending s: min idx in thread
            }
            int bi = tid + bs * 512;
            unsigned kd = __float_as_uint(bv);
            unsigned md = wave_reduce_umax(kd);
            unsigned cand = (kd == md) ? (unsigned)bi : 0xffffffffu;
            unsigned mi = wave_reduce_umin(cand);
            if (lane == 0)
                kbuf[par][w] = ((unsigned long long)md << 32) |
                               (unsigned long long)(0xffffffffu - mi);   // u64 max == lex rule
            __syncthreads();
            // vectorized tree max over 8 wave keys (exact; keys distinct across waves)
            const unsigned long long* kb = kbuf[par];
            ulonglong2 q0 = *(const ulonglong2*)&kb[0];
            ulonglong2 q1 = *(const ulonglong2*)&kb[2];
            ulonglong2 q2 = *(const ulonglong2*)&kb[4];
            ulonglong2 q3 = *(const ulonglong2*)&kb[6];
            unsigned long long a0 = q0.x > q0.y ? q0.x : q0.y;
            unsigned long long a1 = q1.x > q1.y ? q1.x : q1.y;
            unsigned long long a2 = q2.x > q2.y ? q2.x : q2.y;
            unsigned long long a3 = q3.x > q3.y ? q3.x : q3.y;
            unsigned long long b01 = a0 > a1 ? a0 : a1;
            unsigned long long b23 = a2 > a3 ? a2 : a3;
            unsigned long long best = b01 > b23 ? b01 : b23;
            int widx = (int)(0xffffffffu - (unsigned)(best & 0xffffffffull));
            widx = ((unsigned)widx < (unsigned)N_) ? widx : 0;             // fault guard
            float4 wp = pts[widx];                                         // LDS broadcast
            lx = wp.x; ly = wp.y; lz = wp.z;
            if (tid == 0) {
                wlist[m] = widx;
                __hip_atomic_store(&wflag[(size_t)b * M_ + m], (unsigned)widx,
                                   __ATOMIC_RELAXED, __HIP_MEMORY_SCOPE_AGENT);
            }
            par ^= 1;
        }

        // epilogue: out_fps only
        __syncthreads();
        for (int mm = tid; mm < M_; mm += 512) {
            int wi = (mm == 0) ? 0 : wlist[mm];
            wi = ((unsigned)wi < (unsigned)N_) ? wi : 0;                   // fault guard
            float4 wp = pts[wi];
            out_fps[(size_t)b * 3 * M_ + 0 * M_ + mm] = wp.x;
            out_fps[(size_t)b * 3 * M_ + 1 * M_ + mm] = wp.y;
            out_fps[(size_t)b * 3 * M_ + 2 * M_ + mm] = wp.z;
        }
    } else {
        const int wkr = blockIdx.x - B_;          // 0..239

        // ================= GEMM: hp[b][n][o] = sum_c x[b][c][n]*W[o][c] ====
        float (*Xs)[128] = sm.g.Xs;
        float (*Wt)[68] = sm.g.Wt;
        for (int t = wkr; t < NTILE; t += WORKERS) {
            const int b = t >> 8;                 // 256 tiles per batch
            const int rem = t & 255;
            const int n0 = (rem >> 2) * 128;
            const int o0 = (rem & 3) * 64;
            const int tn = (tid & 31) * 4;        // 0..124
            const int to = (tid >> 5) * 4;        // 0..60
            const float* xg = x + (size_t)b * CIN_ * N_;

            float acc[4][4] = {};
            for (int kk = 0; kk < CIN_; kk += 64) {
#pragma unroll
                for (int i = 0; i < 16; ++i) {    // 8192 elems of Xs
                    int e = tid + 512 * i;
                    int r = e >> 7, q = e & 127;
                    Xs[r][q] = xg[(size_t)(kk + r) * N_ + n0 + q];
                }
#pragma unroll
                for (int i = 0; i < 8; ++i) {     // 4096 elems of Wt
                    int e = tid + 512 * i;
                    int r = e >> 6, q = e & 63;
                    Wt[q][r] = W[(size_t)(o0 + r) * CIN_ + kk + q];
                }
                __syncthreads();
#pragma unroll 8
                for (int c = 0; c < 64; ++c) {
                    float4 a = *(const float4*)&Xs[c][tn];
                    float4 bb = *(const float4*)&Wt[c][to];
                    float av[4] = {a.x, a.y, a.z, a.w};
                    float bv[4] = {bb.x, bb.y, bb.z, bb.w};
#pragma unroll
                    for (int j = 0; j < 4; ++j)
#pragma unroll
                        for (int l = 0; l < 4; ++l)
                            acc[j][l] += av[j] * bv[l];
                }
                __syncthreads();
            }
#pragma unroll
            for (int j = 0; j < 4; ++j) {
                float4 v = make_float4(acc[j][0], acc[j][1], acc[j][2], acc[j][3]);
                *(float4*)&hp[((size_t)b * N_ + n0 + tn + j) * COUT_ + o0 + to] = v;
            }
        }

        // ==== device-scope barrier among the 240 workers (all co-resident) ==
        // release(fetch_add) -> acquire(spin) -> __syncthreads gives the
        // happens-before chain: other blocks' hp stores -> our hp gathers.
        __threadfence();
        if (tid == 0) {
            __hip_atomic_fetch_add(gbar, 1, __ATOMIC_RELEASE, __HIP_MEMORY_SCOPE_AGENT);
            while (__hip_atomic_load(gbar, __ATOMIC_ACQUIRE, __HIP_MEMORY_SCOPE_AGENT) < WORKERS)
                __builtin_amdgcn_s_sleep(8);
        }
        __syncthreads();

        // ================= kNN (progressive consumer) + BN stats gather ====
        {
#pragma clang fp contract(off)
            float4* tile = sm.k.tile;
            double sAcc[4] = {0.0, 0.0, 0.0, 0.0};
            double s2Acc[4] = {0.0, 0.0, 0.0, 0.0};

            for (int g = wkr; g < NGROUP; g += WORKERS) {
                const int b = g & 7;
                const int mg = g >> 3;
                const int m = mg * 8 + w;
                const int row = b * M_ + m;
                const float* cb = coords + (size_t)b * 3 * N_;

                unsigned widx;
                while ((widx = __hip_atomic_load(&wflag[row], __ATOMIC_RELAXED,
                                                 __HIP_MEMORY_SCOPE_AGENT)) == 0xffffffffu)
                    __builtin_amdgcn_s_sleep(2);
                widx = (widx < (unsigned)N_) ? widx : 0;   // fault guard

                const float fx = cb[widx];
                const float fy = cb[N_ + widx];
                const float fz = cb[2 * N_ + widx];        // same floats as old fpts
                const float sf = __builtin_fmaf(fz, fz, __builtin_fmaf(fy, fy, fx * fx)); // frozen

                float ed = INFINITY; int ei = 0x7fffffff;  // distributed list entry
                float tau_d = INFINITY; int tau_i = 0x7fffffff;

                for (int t = 0; t < 8; ++t) {
                    const int base = t * 1024;
#pragma unroll
                    for (int j = 0; j < 2; ++j) {
                        int idx = tid + 512 * j;
                        int n = base + idx;
                        float gx = cb[n], gy = cb[N_ + n], gz = cb[2 * N_ + n];
                        float sp = __builtin_fmaf(gz, gz, __builtin_fmaf(gy, gy, gx * gx)); // frozen
                        tile[idx] = make_float4(gx, gy, gz, sp);
                    }
                    __syncthreads();
                    for (int s = 0; s < 16; ++s) {
                        int l = s * 64 + lane;
                        float4 p = tile[l];
                        int n = base + l;
                        float dot = __builtin_fmaf(fz, p.z, __builtin_fmaf(fy, p.y, fx * p.x)); // frozen
                        float d = (sf + p.w) - 2.0f * dot;                                      // frozen
                        bool q = (d < tau_d) || (d == tau_d && n < tau_i);
                        unsigned long long bal = __ballot(q);
                        while (bal) {
                            int lb = __ffsll(bal) - 1;
                            bal &= bal - 1;
                            float dv = __shfl(d, lb);
                            int   iv = __shfl(n, lb);
                            if ((dv < tau_d) || (dv == tau_d && iv < tau_i)) {
                                float pud = __shfl_up(ed, 1);
                                int   pui = __shfl_up(ei, 1);
                                bool cs = (dv < ed) || (dv == ed && iv < ei);
                                bool cp = (lane != 0) && ((dv < pud) || (dv == pud && iv < pui));
                                ed = cs ? (cp ? pud : dv) : ed;
                                ei = cs ? (cp ? pui : iv) : ei;
                                tau_d = __shfl(ed, 15);
                                tau_i = __shfl(ei, 15);
                            }
                        }
                    }
                    __syncthreads();
                }
                if (lane < K_) {
                    int v = ei;
                    v = ((unsigned)v < (unsigned)N_) ? v : 0;          // fault guard
                    knn[(size_t)row * K_ + lane] = v;
                }
                // BN stats gather: 16 neighbor hp rows, per-o f64 sums.
                // lane L owns o = L + 64j. Hidden under FPS (workers
                // otherwise idle-spin); hp safe to read after the barrier.
#pragma unroll
                for (int k = 0; k < K_; ++k) {
                    int iv = __shfl(ei, k);
                    iv = ((unsigned)iv < (unsigned)N_) ? iv : 0;       // fault guard
                    const float* hrow = hp + ((size_t)b * N_ + iv) * COUT_;
#pragma unroll
                    for (int j = 0; j < 4; ++j) {
                        double h = (double)hrow[lane + 64 * j];
                        sAcc[j] += h;
                        s2Acc[j] += h * h;
                    }
                }
            }

            // per-wave partials -> LDS (private slots), cross-wave reduce,
            // block partial to fixed global slot (no atomics, deterministic).
            double (*wacc)[512] = sm.k.wacc;
#pragma unroll
            for (int j = 0; j < 4; ++j) {
                wacc[w][lane + 64 * j] = sAcc[j];
                wacc[w][256 + lane + 64 * j] = s2Acc[j];
            }
            __syncthreads();
            double tsum = 0.0;
#pragma unroll
            for (int wv = 0; wv < 8; ++wv) tsum += wacc[wv][tid];
            partial[(size_t)wkr * 512 + tid] = tsum;
        }
    }
}

// ---------------------------------------------------------------------------
// BN final: reduce 240 block partials per o; scale/bias as before.
// ---------------------------------------------------------------------------
__global__ void bn_final_kernel(const double* __restrict__ partial,
                                const float* __restrict__ gamma,
                                const float* __restrict__ beta,
                                float* __restrict__ scale,
                                float* __restrict__ bias) {
    int o = threadIdx.x;
    double s = 0.0, s2 = 0.0;
    for (int j = 0; j < WORKERS; ++j) {
        s += partial[(size_t)j * 512 + o];
        s2 += partial[(size_t)j * 512 + 256 + o];
    }
    const double inv = 1.0 / (double)(B_ * M_ * K_);
    double mean = s * inv;
    double var = s2 * inv - mean * mean;
    if (var < 0.0) var = 0.0;
    double r = 1.0 / sqrt(var + 1e-5);
    double g = (double)gamma[o];
    scale[o] = (float)(r * g);
    bias[o] = (float)((double)beta[o] - mean * r * g);
}

// ---------------------------------------------------------------------------
// Finalize: y[b][o][m] = relu( max_k ( hp[gather] * scale + bias ) ) (unchanged)
// ---------------------------------------------------------------------------
__global__ __launch_bounds__(256) void finalize_kernel(const float* __restrict__ hp,
                                                       const int* __restrict__ knn,
                                                       const float* __restrict__ scale,
                                                       const float* __restrict__ bias,
                                                       float* __restrict__ y) {
    const int b = blockIdx.x >> 6;
    const int m0 = (blockIdx.x & 63) * 32;
    const int tid = threadIdx.x;
    __shared__ int kidx[512];
    __shared__ float tile[32][257];

    for (int e = tid; e < 512; e += 256) {
        int n = knn[(b * M_ + m0 + (e >> 4)) * K_ + (e & 15)];
        kidx[e] = ((unsigned)n < (unsigned)N_) ? n : 0;   // fault guard
    }
    __syncthreads();

    const float s = scale[tid];
    const float t = bias[tid];
    const float* hb = hp + (size_t)b * N_ * COUT_;
    for (int mm = 0; mm < 32; ++mm) {
        float v = -INFINITY;
#pragma unroll
        for (int k = 0; k < K_; ++k) {
            int n = kidx[mm * 16 + k];
            float h = hb[(size_t)n * COUT_ + tid];
            v = fmaxf(v, h * s + t);
        }
        v = fmaxf(v, 0.0f);
        tile[mm][tid] = v;
    }
    __syncthreads();
#pragma unroll
    for (int r = 0; r < 32; ++r) {
        int o2 = r * 8 + (tid >> 5);
        int mm = tid & 31;
        y[((size_t)b * COUT_ + o2) * M_ + m0 + mm] = tile[mm][o2];
    }
}

__global__ void sentinel_kernel(float* out, float v) { out[0] = v; }

// ---------------------------------------------------------------------------
extern "C" void kernel_launch(void* const* d_in, const int* in_sizes, int n_in,
                              void* d_out, int out_size, void* d_ws, size_t ws_size,
                              hipStream_t stream) {
    const float* x = (const float*)d_in[0];
    const float* coords = (const float*)d_in[1];
    const float* W = (const float*)d_in[2];
    const float* gamma = (const float*)d_in[3];
    const float* beta = (const float*)d_in[4];
    float* y = (float*)d_out;
    float* out_fps = y + (size_t)B_ * COUT_ * M_;     // fps_coords after y (f32)

    if (n_in != 5 ||
        in_sizes[0] != B_ * CIN_ * N_ ||
        in_sizes[1] != B_ * 3 * N_ ||
        in_sizes[2] != COUT_ * CIN_ ||
        in_sizes[3] != COUT_ || in_sizes[4] != COUT_ ||
        out_size != B_ * COUT_ * M_ + B_ * 3 * M_) {
        sentinel_kernel<<<1, 1, 0, stream>>>(y, -2.0e6f);
        return;
    }

    const size_t HP_BYTES = (size_t)B_ * N_ * COUT_ * 4;          // 64 MB
    const size_t KNN_BYTES = (size_t)B_ * M_ * K_ * 4;            // 1 MB
    const size_t PART_BYTES = (size_t)WORKERS * 512 * 8;          // 983 KB
    const size_t WFLAG_BYTES = (size_t)B_ * M_ * 4;               // 64 KB
    const size_t NEED = HP_BYTES + KNN_BYTES + PART_BYTES + WFLAG_BYTES + 8192;
    if (ws_size < NEED) {
        sentinel_kernel<<<1, 1, 0, stream>>>(y, -1.0e6f);
        return;
    }
    char* ws = (char*)d_ws;
    float* hp = (float*)ws;
    int* knn = (int*)(ws + HP_BYTES);
    double* partial = (double*)(ws + HP_BYTES + KNN_BYTES);
    unsigned* wflag = (unsigned*)(ws + HP_BYTES + KNN_BYTES + PART_BYTES);
    char* tail = ws + HP_BYTES + KNN_BYTES + PART_BYTES + WFLAG_BYTES;
    int* gbar = (int*)tail;                                        // 4 B
    float* scale = (float*)(tail + 256);
    float* bias = scale + 256;

    (void)hipMemsetAsync(wflag, 0xFF, WFLAG_BYTES, stream);        // winner flags = empty
    (void)hipMemsetAsync(gbar, 0, 256, stream);                    // worker barrier = 0

    mega_kernel<<<B_ + WORKERS, 512, 0, stream>>>(coords, x, W, wflag, out_fps,
                                                  hp, knn, partial, gbar);
    bn_final_kernel<<<1, 256, 0, stream>>>(partial, gamma, beta, scale, bias);
    finalize_kernel<<<512, 256, 0, stream>>>(hp, knn, scale, bias, y);
}

// Round 10
// 1668.977 us; speedup vs baseline: 1.1383x; 1.0259x over previous
//
#include <hip/hip_runtime.h>
#include <math.h>

#define B_ 8
#define CIN_ 128
#define COUT_ 256
#define N_ 8192
#define M_ 2048
#define K_ 16

#define WORKERS 240          // non-FPS blocks in the mega kernel
#define NTILE 2048           // gemm: 8 b x 256 tiles (128n x 64o)
#define NGROUP 2048          // knn: 8 b x 256 groups of 8 rows

// ---------------------------------------------------------------------------
// DPP wave reductions (row_shr 1/2/4/8 + row_bcast 15/31): VALU-latency only.
// (R1/v4 exact form — measured best fps; R2/R3 restructures both lost.)
// ---------------------------------------------------------------------------
__device__ __forceinline__ unsigned umax2(unsigned a, unsigned b) { return a > b ? a : b; }
__device__ __forceinline__ unsigned umin2(unsigned a, unsigned b) { return a < b ? a : b; }

__device__ __forceinline__ unsigned wave_reduce_umax(unsigned v) {
    v = umax2(v, (unsigned)__builtin_amdgcn_update_dpp(0, (int)v, 0x111, 0xf, 0xf, false));
    v = umax2(v, (unsigned)__builtin_amdgcn_update_dpp(0, (int)v, 0x112, 0xf, 0xf, false));
    v = umax2(v, (unsigned)__builtin_amdgcn_update_dpp(0, (int)v, 0x114, 0xf, 0xf, false));
    v = umax2(v, (unsigned)__builtin_amdgcn_update_dpp(0, (int)v, 0x118, 0xf, 0xf, false));
    v = umax2(v, (unsigned)__builtin_amdgcn_update_dpp(0, (int)v, 0x142, 0xf, 0xf, false));
    v = umax2(v, (unsigned)__builtin_amdgcn_update_dpp(0, (int)v, 0x143, 0xf, 0xf, false));
    return (unsigned)__builtin_amdgcn_readlane((int)v, 63);
}
__device__ __forceinline__ unsigned wave_reduce_umin(unsigned v) {
    v = umin2(v, (unsigned)__builtin_amdgcn_update_dpp(-1, (int)v, 0x111, 0xf, 0xf, false));
    v = umin2(v, (unsigned)__builtin_amdgcn_update_dpp(-1, (int)v, 0x112, 0xf, 0xf, false));
    v = umin2(v, (unsigned)__builtin_amdgcn_update_dpp(-1, (int)v, 0x114, 0xf, 0xf, false));
    v = umin2(v, (unsigned)__builtin_amdgcn_update_dpp(-1, (int)v, 0x118, 0xf, 0xf, false));
    v = umin2(v, (unsigned)__builtin_amdgcn_update_dpp(-1, (int)v, 0x142, 0xf, 0xf, false));
    v = umin2(v, (unsigned)__builtin_amdgcn_update_dpp(-1, (int)v, 0x143, 0xf, 0xf, false));
    return (unsigned)__builtin_amdgcn_readlane((int)v, 63);
}

// ---------------------------------------------------------------------------
// MEGA kernel (producer-consumer, R9 structure + fused k-max + folded BN):
//   blocks 0..7    : FPS (R1/v4 verbatim) + progressive winner publication.
//   blocks 8..247  : GEMM -> worker barrier #1 -> knn groups ascending-m
//                    (spin on wflag); per row: BN f64 gather (R9-verified)
//                    PLUS per-o k-max (same loads, extra fmaxf) stored
//                    directly to y's final transposed address; then worker
//                    barrier #2 arrive; block wkr==0 computes scale/bias
//                    (IDENTICAL summation order to old bn_final).
// finalize then reduces to in-place elementwise y = relu(s*y+t): for s>=0
// float mul/add is weakly monotone, so max_k(h*s+t) == (max_k h)*s+t with
// the same expression -> y BIT-IDENTICAL (s<0 handled by gather fallback).
// FPS / knn / GEMM / BN summation order all FROZEN.
// ---------------------------------------------------------------------------
__global__ __launch_bounds__(512) void mega_kernel(const float* __restrict__ coords,
                                                   const float* __restrict__ x,
                                                   const float* __restrict__ W,
                                                   unsigned* __restrict__ wflag,
                                                   float* __restrict__ out_fps,
                                                   float* __restrict__ hp,
                                                   int* __restrict__ knn,
                                                   double* __restrict__ partial,
                                                   int* __restrict__ gbar,
                                                   float* __restrict__ ymax,
                                                   const float* __restrict__ gamma,
                                                   const float* __restrict__ beta,
                                                   float* __restrict__ scale,
                                                   float* __restrict__ bias) {
    __shared__ union {
        struct {
            float4 pts[N_];                      // 128 KiB
            unsigned long long kbuf[2][8];
            int wlist[M_];                       // 8 KiB
        } f;
        struct {
            float Xs[64][128];                   // 32 KiB
            float Wt[64][68];                    // 17 KiB
        } g;
        struct {
            float4 tile[1024];                   // 16 KiB
            double wacc[8][512];                 // 32 KiB (per-wave partials)
        } k;
    } sm;

    const int tid = threadIdx.x;
    const int lane = tid & 63;
    const int w = tid >> 6;                      // wave id 0..7

    if (blockIdx.x < B_) {
        // ================= FPS (R1/v4 exact + winner publication) ==========
#pragma clang fp contract(off)
        const int b = blockIdx.x;
        const float* cb = coords + (size_t)b * 3 * N_;
        float4* pts = sm.f.pts;
        unsigned long long (*kbuf)[8] = sm.f.kbuf;
        int* wlist = sm.f.wlist;

        float px[16], py[16], pz[16], mind[16];
#pragma unroll
        for (int s = 0; s < 16; ++s) {
            int p = tid + s * 512;
            px[s] = cb[p];
            py[s] = cb[N_ + p];
            pz[s] = cb[2 * N_ + p];
            mind[s] = 1e10f;
            pts[p] = make_float4(px[s], py[s], pz[s], 0.f);
        }
        if (tid == 0)
            __hip_atomic_store(&wflag[(size_t)b * M_], 0u,
                               __ATOMIC_RELAXED, __HIP_MEMORY_SCOPE_AGENT);
        __syncthreads();
        float4 p0 = pts[0];
        float lx = p0.x, ly = p0.y, lz = p0.z;

        int par = 0;
        for (int m = 1; m < M_; ++m) {
            float bv = -1.0f; int bs = 0;
#pragma unroll
            for (int s = 0; s < 16; ++s) {
                float dx = px[s] - lx;
                float dy = py[s] - ly;
                float dz = pz[s] - lz;
                float d = __builtin_fmaf(dz, dz, __builtin_fmaf(dy, dy, dx * dx));  // frozen
                float mn = fminf(mind[s], d);
                mind[s] = mn;
                if (mn > bv) { bv = mn; bs = s; }   // strict >, ascending s: min idx in thread
            }
            int bi = tid + bs * 512;
            unsigned kd = __float_as_uint(bv);
            unsigned md = wave_reduce_umax(kd);
            unsigned cand = (kd == md) ? (unsigned)bi : 0xffffffffu;
            unsigned mi = wave_reduce_umin(cand);
            if (lane == 0)
                kbuf[par][w] = ((unsigned long long)md << 32) |
                               (unsigned long long)(0xffffffffu - mi);   // u64 max == lex rule
            __syncthreads();
            // vectorized tree max over 8 wave keys (exact; keys distinct across waves)
            const unsigned long long* kb = kbuf[par];
            ulonglong2 q0 = *(const ulonglong2*)&kb[0];
            ulonglong2 q1 = *(const ulonglong2*)&kb[2];
            ulonglong2 q2 = *(const ulonglong2*)&kb[4];
            ulonglong2 q3 = *(const ulonglong2*)&kb[6];
            unsigned long long a0 = q0.x > q0.y ? q0.x : q0.y;
            unsigned long long a1 = q1.x > q1.y ? q1.x : q1.y;
            unsigned long long a2 = q2.x > q2.y ? q2.x : q2.y;
            unsigned long long a3 = q3.x > q3.y ? q3.x : q3.y;
            unsigned long long b01 = a0 > a1 ? a0 : a1;
            unsigned long long b23 = a2 > a3 ? a2 : a3;
            unsigned long long best = b01 > b23 ? b01 : b23;
            int widx = (int)(0xffffffffu - (unsigned)(best & 0xffffffffull));
            widx = ((unsigned)widx < (unsigned)N_) ? widx : 0;             // fault guard
            float4 wp = pts[widx];                                         // LDS broadcast
            lx = wp.x; ly = wp.y; lz = wp.z;
            if (tid == 0) {
                wlist[m] = widx;
                __hip_atomic_store(&wflag[(size_t)b * M_ + m], (unsigned)widx,
                                   __ATOMIC_RELAXED, __HIP_MEMORY_SCOPE_AGENT);
            }
            par ^= 1;
        }

        // epilogue: out_fps only
        __syncthreads();
        for (int mm = tid; mm < M_; mm += 512) {
            int wi = (mm == 0) ? 0 : wlist[mm];
            wi = ((unsigned)wi < (unsigned)N_) ? wi : 0;                   // fault guard
            float4 wp = pts[wi];
            out_fps[(size_t)b * 3 * M_ + 0 * M_ + mm] = wp.x;
            out_fps[(size_t)b * 3 * M_ + 1 * M_ + mm] = wp.y;
            out_fps[(size_t)b * 3 * M_ + 2 * M_ + mm] = wp.z;
        }
    } else {
        const int wkr = blockIdx.x - B_;          // 0..239

        // ================= GEMM: hp[b][n][o] = sum_c x[b][c][n]*W[o][c] ====
        float (*Xs)[128] = sm.g.Xs;
        float (*Wt)[68] = sm.g.Wt;
        for (int t = wkr; t < NTILE; t += WORKERS) {
            const int b = t >> 8;                 // 256 tiles per batch
            const int rem = t & 255;
            const int n0 = (rem >> 2) * 128;
            const int o0 = (rem & 3) * 64;
            const int tn = (tid & 31) * 4;        // 0..124
            const int to = (tid >> 5) * 4;        // 0..60
            const float* xg = x + (size_t)b * CIN_ * N_;

            float acc[4][4] = {};
            for (int kk = 0; kk < CIN_; kk += 64) {
#pragma unroll
                for (int i = 0; i < 16; ++i) {    // 8192 elems of Xs
                    int e = tid + 512 * i;
                    int r = e >> 7, q = e & 127;
                    Xs[r][q] = xg[(size_t)(kk + r) * N_ + n0 + q];
                }
#pragma unroll
                for (int i = 0; i < 8; ++i) {     // 4096 elems of Wt
                    int e = tid + 512 * i;
                    int r = e >> 6, q = e & 63;
                    Wt[q][r] = W[(size_t)(o0 + r) * CIN_ + kk + q];
                }
                __syncthreads();
#pragma unroll 8
                for (int c = 0; c < 64; ++c) {
                    float4 a = *(const float4*)&Xs[c][tn];
                    float4 bb = *(const float4*)&Wt[c][to];
                    float av[4] = {a.x, a.y, a.z, a.w};
                    float bv[4] = {bb.x, bb.y, bb.z, bb.w};
#pragma unroll
                    for (int j = 0; j < 4; ++j)
#pragma unroll
                        for (int l = 0; l < 4; ++l)
                            acc[j][l] += av[j] * bv[l];
                }
                __syncthreads();
            }
#pragma unroll
            for (int j = 0; j < 4; ++j) {
                float4 v = make_float4(acc[j][0], acc[j][1], acc[j][2], acc[j][3]);
                *(float4*)&hp[((size_t)b * N_ + n0 + tn + j) * COUT_ + o0 + to] = v;
            }
        }

        // ==== worker barrier #1 (all 240 co-resident; R9-verified pattern) ==
        __threadfence();
        if (tid == 0) {
            __hip_atomic_fetch_add(&gbar[0], 1, __ATOMIC_RELEASE, __HIP_MEMORY_SCOPE_AGENT);
            while (__hip_atomic_load(&gbar[0], __ATOMIC_ACQUIRE, __HIP_MEMORY_SCOPE_AGENT) < WORKERS)
                __builtin_amdgcn_s_sleep(8);
        }
        __syncthreads();

        // ======== kNN (progressive consumer) + BN stats + fused k-max ======
        {
#pragma clang fp contract(off)
            float4* tile = sm.k.tile;
            double sAcc[4] = {0.0, 0.0, 0.0, 0.0};
            double s2Acc[4] = {0.0, 0.0, 0.0, 0.0};

            for (int g = wkr; g < NGROUP; g += WORKERS) {
                const int b = g & 7;
                const int mg = g >> 3;
                const int m = mg * 8 + w;
                const int row = b * M_ + m;
                const float* cb = coords + (size_t)b * 3 * N_;

                unsigned widx;
                while ((widx = __hip_atomic_load(&wflag[row], __ATOMIC_RELAXED,
                                                 __HIP_MEMORY_SCOPE_AGENT)) == 0xffffffffu)
                    __builtin_amdgcn_s_sleep(2);
                widx = (widx < (unsigned)N_) ? widx : 0;   // fault guard

                const float fx = cb[widx];
                const float fy = cb[N_ + widx];
                const float fz = cb[2 * N_ + widx];        // same floats as old fpts
                const float sf = __builtin_fmaf(fz, fz, __builtin_fmaf(fy, fy, fx * fx)); // frozen

                float ed = INFINITY; int ei = 0x7fffffff;  // distributed list entry
                float tau_d = INFINITY; int tau_i = 0x7fffffff;

                for (int t = 0; t < 8; ++t) {
                    const int base = t * 1024;
#pragma unroll
                    for (int j = 0; j < 2; ++j) {
                        int idx = tid + 512 * j;
                        int n = base + idx;
                        float gx = cb[n], gy = cb[N_ + n], gz = cb[2 * N_ + n];
                        float sp = __builtin_fmaf(gz, gz, __builtin_fmaf(gy, gy, gx * gx)); // frozen
                        tile[idx] = make_float4(gx, gy, gz, sp);
                    }
                    __syncthreads();
                    for (int s = 0; s < 16; ++s) {
                        int l = s * 64 + lane;
                        float4 p = tile[l];
                        int n = base + l;
                        float dot = __builtin_fmaf(fz, p.z, __builtin_fmaf(fy, p.y, fx * p.x)); // frozen
                        float d = (sf + p.w) - 2.0f * dot;                                      // frozen
                        bool q = (d < tau_d) || (d == tau_d && n < tau_i);
                        unsigned long long bal = __ballot(q);
                        while (bal) {
                            int lb = __ffsll(bal) - 1;
                            bal &= bal - 1;
                            float dv = __shfl(d, lb);
                            int   iv = __shfl(n, lb);
                            if ((dv < tau_d) || (dv == tau_d && iv < tau_i)) {
                                float pud = __shfl_up(ed, 1);
                                int   pui = __shfl_up(ei, 1);
                                bool cs = (dv < ed) || (dv == ed && iv < ei);
                                bool cp = (lane != 0) && ((dv < pud) || (dv == pud && iv < pui));
                                ed = cs ? (cp ? pud : dv) : ed;
                                ei = cs ? (cp ? pui : iv) : ei;
                                tau_d = __shfl(ed, 15);
                                tau_i = __shfl(ei, 15);
                            }
                        }
                    }
                    __syncthreads();
                }
                if (lane < K_) {
                    int v = ei;
                    v = ((unsigned)v < (unsigned)N_) ? v : 0;          // fault guard
                    knn[(size_t)row * K_ + lane] = v;
                }
                // BN stats + k-max over the SAME loads. lane L owns o = L+64j.
                float mx[4] = {-INFINITY, -INFINITY, -INFINITY, -INFINITY};
#pragma unroll
                for (int k = 0; k < K_; ++k) {
                    int iv = __shfl(ei, k);
                    iv = ((unsigned)iv < (unsigned)N_) ? iv : 0;       // fault guard
                    const float* hrow = hp + ((size_t)b * N_ + iv) * COUT_;
#pragma unroll
                    for (int j = 0; j < 4; ++j) {
                        float hv = hrow[lane + 64 * j];
                        double h = (double)hv;
                        sAcc[j] += h;
                        s2Acc[j] += h * h;
                        mx[j] = fmaxf(mx[j], hv);
                    }
                }
                // store k-max at its FINAL transposed y address (hidden scatter)
#pragma unroll
                for (int j = 0; j < 4; ++j)
                    ymax[((size_t)b * COUT_ + (lane + 64 * j)) * M_ + m] = mx[j];
            }

            // per-wave partials -> LDS, cross-wave reduce, block partial out
            double (*wacc)[512] = sm.k.wacc;
#pragma unroll
            for (int j = 0; j < 4; ++j) {
                wacc[w][lane + 64 * j] = sAcc[j];
                wacc[w][256 + lane + 64 * j] = s2Acc[j];
            }
            __syncthreads();
            double tsum = 0.0;
#pragma unroll
            for (int wv = 0; wv < 8; ++wv) tsum += wacc[wv][tid];
            partial[(size_t)wkr * 512 + tid] = tsum;
        }

        // ==== worker barrier #2 arrive; block 0 computes scale/bias ========
        __threadfence();
        if (tid == 0)
            __hip_atomic_fetch_add(&gbar[1], 1, __ATOMIC_RELEASE, __HIP_MEMORY_SCOPE_AGENT);
        if (wkr == 0) {
            if (tid == 0) {
                while (__hip_atomic_load(&gbar[1], __ATOMIC_ACQUIRE, __HIP_MEMORY_SCOPE_AGENT) < WORKERS)
                    __builtin_amdgcn_s_sleep(8);
            }
            __syncthreads();
            if (tid < 256) {
                int o = tid;
                double s = 0.0, s2 = 0.0;
                for (int j = 0; j < WORKERS; ++j) {          // IDENTICAL order to old bn_final
                    s += partial[(size_t)j * 512 + o];
                    s2 += partial[(size_t)j * 512 + 256 + o];
                }
                const double inv = 1.0 / (double)(B_ * M_ * K_);
                double mean = s * inv;
                double var = s2 * inv - mean * mean;
                if (var < 0.0) var = 0.0;
                double r = 1.0 / sqrt(var + 1e-5);
                double gm = (double)gamma[o];
                scale[o] = (float)(r * gm);
                bias[o] = (float)((double)beta[o] - mean * r * gm);
            }
        }
    }
}

// ---------------------------------------------------------------------------
// Finalize: y holds mx = max_k hp (written by mega at final addresses).
// s>=0: y = relu(s*mx+t) in place — BIT-IDENTICAL to relu(max_k(h*s+t))
// since mul/add by (s>=0, t) is weakly monotone in float. s<0 fallback
// keeps general correctness via the old gather form (max -> min flip).
// ---------------------------------------------------------------------------
__global__ __launch_bounds__(256) void finalize_kernel(const float* __restrict__ hp,
                                                       const int* __restrict__ knn,
                                                       const float* __restrict__ scale,
                                                       const float* __restrict__ bias,
                                                       float* __restrict__ y) {
    const int b = blockIdx.x >> 8;            // 2048 blocks: (b, o)
    const int o = blockIdx.x & 255;
    const float s = scale[o];
    const float t = bias[o];
    float* yrow = y + ((size_t)b * COUT_ + o) * M_;
    const int tid = threadIdx.x;
    if (s >= 0.0f) {
#pragma unroll
        for (int i = 0; i < 8; ++i) {
            int m = tid + 256 * i;
            float h = yrow[m];                // mx
            float v = h * s + t;              // same expression as old per-k form
            yrow[m] = fmaxf(v, 0.0f);
        }
    } else {
        for (int i = 0; i < 8; ++i) {
            int m = tid + 256 * i;
            float v = -INFINITY;
            for (int k = 0; k < K_; ++k) {
                int n = knn[(size_t)(b * M_ + m) * K_ + k];
                n = ((unsigned)n < (unsigned)N_) ? n : 0;   // fault guard
                float h = hp[((size_t)b * N_ + n) * COUT_ + o];
                v = fmaxf(v, h * s + t);
            }
            yrow[m] = fmaxf(v, 0.0f);
        }
    }
}

__global__ void sentinel_kernel(float* out, float v) { out[0] = v; }

// ---------------------------------------------------------------------------
extern "C" void kernel_launch(void* const* d_in, const int* in_sizes, int n_in,
                              void* d_out, int out_size, void* d_ws, size_t ws_size,
                              hipStream_t stream) {
    const float* x = (const float*)d_in[0];
    const float* coords = (const float*)d_in[1];
    const float* W = (const float*)d_in[2];
    const float* gamma = (const float*)d_in[3];
    const float* beta = (const float*)d_in[4];
    float* y = (float*)d_out;
    float* out_fps = y + (size_t)B_ * COUT_ * M_;     // fps_coords after y (f32)

    if (n_in != 5 ||
        in_sizes[0] != B_ * CIN_ * N_ ||
        in_sizes[1] != B_ * 3 * N_ ||
        in_sizes[2] != COUT_ * CIN_ ||
        in_sizes[3] != COUT_ || in_sizes[4] != COUT_ ||
        out_size != B_ * COUT_ * M_ + B_ * 3 * M_) {
        sentinel_kernel<<<1, 1, 0, stream>>>(y, -2.0e6f);
        return;
    }

    const size_t HP_BYTES = (size_t)B_ * N_ * COUT_ * 4;          // 64 MB
    const size_t KNN_BYTES = (size_t)B_ * M_ * K_ * 4;            // 1 MB
    const size_t PART_BYTES = (size_t)WORKERS * 512 * 8;          // 983 KB
    const size_t WFLAG_BYTES = (size_t)B_ * M_ * 4;               // 64 KB
    const size_t NEED = HP_BYTES + KNN_BYTES + PART_BYTES + WFLAG_BYTES + 8192;
    if (ws_size < NEED) {
        sentinel_kernel<<<1, 1, 0, stream>>>(y, -1.0e6f);
        return;
    }
    char* ws = (char*)d_ws;
    float* hp = (float*)ws;
    int* knn = (int*)(ws + HP_BYTES);
    double* partial = (double*)(ws + HP_BYTES + KNN_BYTES);
    unsigned* wflag = (unsigned*)(ws + HP_BYTES + KNN_BYTES + PART_BYTES);
    char* tail = ws + HP_BYTES + KNN_BYTES + PART_BYTES + WFLAG_BYTES;
    int* gbar = (int*)tail;                                        // 2 counters
    float* scale = (float*)(tail + 256);
    float* bias = scale + 256;

    (void)hipMemsetAsync(wflag, 0xFF, WFLAG_BYTES, stream);        // winner flags = empty
    (void)hipMemsetAsync(gbar, 0, 256, stream);                    // both barriers = 0

    mega_kernel<<<B_ + WORKERS, 512, 0, stream>>>(coords, x, W, wflag, out_fps,
                                                  hp, knn, partial, gbar, y,
                                                  gamma, beta, scale, bias);
    finalize_kernel<<<B_ * COUT_, 256, 0, stream>>>(hp, knn, scale, bias, y);
}